// Round 1
// baseline (498.393 us; speedup 1.0000x reference)
//
#include <hip/hip_runtime.h>
#include <hip/hip_bf16.h>

#define NNODES 12288
#define NEDGES (NNODES * 32)

typedef __attribute__((ext_vector_type(4))) float f32x4;
typedef __attribute__((ext_vector_type(8))) __bf16 bf16x8;

// ---------------- CSR build ----------------
__global__ void hist_kernel(const int* __restrict__ row, int* __restrict__ cnt) {
    int e = blockIdx.x * 256 + threadIdx.x;
    atomicAdd(&cnt[row[e]], 1);
}

__global__ void scan_kernel(const int* __restrict__ cnt, int* __restrict__ row_ptr,
                            int* __restrict__ fill) {
    __shared__ int lds[1024];
    int t = threadIdx.x;
    int local[12];
    int s = 0;
#pragma unroll
    for (int i = 0; i < 12; i++) { local[i] = cnt[t * 12 + i]; s += local[i]; }
    lds[t] = s;
    __syncthreads();
    for (int off = 1; off < 1024; off <<= 1) {
        int v = lds[t];
        int add = (t >= off) ? lds[t - off] : 0;
        __syncthreads();
        lds[t] = v + add;
        __syncthreads();
    }
    int ex = (t == 0) ? 0 : lds[t - 1];
#pragma unroll
    for (int i = 0; i < 12; i++) {
        row_ptr[t * 12 + i] = ex;
        fill[t * 12 + i] = ex;
        ex += local[i];
    }
    if (t == 1023) row_ptr[NNODES] = ex;
}

__global__ void scatter_kernel(const int* __restrict__ row, const int* __restrict__ col,
                               const float* __restrict__ w, int* __restrict__ fill,
                               int* __restrict__ col_s, float* __restrict__ w_s) {
    int e = blockIdx.x * 256 + threadIdx.x;
    int r = row[e];
    int p = atomicAdd(&fill[r], 1);
    col_s[p] = col[e];
    w_s[p] = w[e];
}

// ---------------- dense layer GEMM (f32, vector ALU) ----------------
// C[M,Nc] = act(A[M,K] @ W[K,Nc]); BM=64,BN=64,BK=16, 256 thr, 4x4 micro-tile
template <bool TANH>
__global__ __launch_bounds__(256) void gemm_act(const float* __restrict__ A,
                                                const float* __restrict__ W,
                                                float* __restrict__ C,
                                                int M, int K, int Nc) {
    __shared__ float As[16][68];  // [k][m], padded: 68*4B stride keeps 16B align + no conflicts
    __shared__ float Ws[16][64];  // [k][n]
    int tid = threadIdx.x;
    int tx = tid & 15, ty = tid >> 4;
    int m0 = blockIdx.y * 64, n0 = blockIdx.x * 64;
    int lm = tid >> 2;          // 0..63 row of A tile
    int lk4 = (tid & 3) * 4;    // k quad
    int wk = tid >> 4;          // 0..15 row of W tile
    int wn4 = (tid & 15) * 4;   // n quad
    float acc[4][4] = {};
    for (int k0 = 0; k0 < K; k0 += 16) {
        f32x4 av = *(const f32x4*)(A + (size_t)(m0 + lm) * K + k0 + lk4);
        f32x4 wv = *(const f32x4*)(W + (size_t)(k0 + wk) * Nc + n0 + wn4);
#pragma unroll
        for (int j = 0; j < 4; j++) As[lk4 + j][lm] = av[j];
        *(f32x4*)&Ws[wk][wn4] = wv;
        __syncthreads();
#pragma unroll
        for (int kk = 0; kk < 16; kk++) {
            f32x4 a = *(const f32x4*)&As[kk][ty * 4];
            f32x4 b = *(const f32x4*)&Ws[kk][tx * 4];
#pragma unroll
            for (int i = 0; i < 4; i++)
#pragma unroll
                for (int j = 0; j < 4; j++) acc[i][j] = fmaf(a[i], b[j], acc[i][j]);
        }
        __syncthreads();
    }
#pragma unroll
    for (int i = 0; i < 4; i++) {
        f32x4 o;
#pragma unroll
        for (int j = 0; j < 4; j++) {
            float v = acc[i][j];
            o[j] = TANH ? tanhf(v) : v;
        }
        *(f32x4*)(C + (size_t)(m0 + ty * 4 + i) * Nc + n0 + tx * 4) = o;
    }
}

// ---------------- SpMM from CSR ----------------
// out[r,f] = sum_e w_s[e] * h[col_s[e], f] over e in [row_ptr[r], row_ptr[r+1])
template <int F, bool WB>
__global__ __launch_bounds__(256) void spmm_kernel(const int* __restrict__ row_ptr,
                                                   const int* __restrict__ col_s,
                                                   const float* __restrict__ w_s,
                                                   const float* __restrict__ h,
                                                   float* __restrict__ out,
                                                   __hip_bfloat16* __restrict__ out_bf) {
    constexpr int RPB = 256 / F;
    int r = blockIdx.x * RPB + (threadIdx.x / F);
    int f = threadIdx.x & (F - 1);
    int e0 = row_ptr[r], e1 = row_ptr[r + 1];
    float acc = 0.f;
    for (int e = e0; e < e1; e++) {
        acc = fmaf(w_s[e], h[(size_t)col_s[e] * F + f], acc);
    }
    out[(size_t)r * F + f] = acc;
    if (WB) out_bf[(size_t)r * F + f] = __float2bfloat16(acc);
}

// ---------------- adj = sigmoid(Z Z^T), Z bf16 [N,64], MFMA 16x16x32 ----------------
__global__ __launch_bounds__(256) void zzt_sigmoid(const __bf16* __restrict__ Z,
                                                   float* __restrict__ out) {
    int wave = threadIdx.x >> 6;
    int lane = threadIdx.x & 63;
    int lr = lane & 15;   // fragment row (A) / col (B)
    int kg = lane >> 4;   // k-group
    int r0 = blockIdx.y * 64;
    int c0 = blockIdx.x * 256 + wave * 64;
    bf16x8 af[4][2], bfr[4][2];
#pragma unroll
    for (int i = 0; i < 4; i++)
#pragma unroll
        for (int ks = 0; ks < 2; ks++) {
            af[i][ks]  = *(const bf16x8*)(Z + (size_t)(r0 + i * 16 + lr) * 64 + ks * 32 + kg * 8);
            bfr[i][ks] = *(const bf16x8*)(Z + (size_t)(c0 + i * 16 + lr) * 64 + ks * 32 + kg * 8);
        }
    f32x4 acc[4][4];
#pragma unroll
    for (int mi = 0; mi < 4; mi++)
#pragma unroll
        for (int ni = 0; ni < 4; ni++) acc[mi][ni] = (f32x4){0.f, 0.f, 0.f, 0.f};
#pragma unroll
    for (int mi = 0; mi < 4; mi++)
#pragma unroll
        for (int ni = 0; ni < 4; ni++) {
            acc[mi][ni] = __builtin_amdgcn_mfma_f32_16x16x32_bf16(af[mi][0], bfr[ni][0], acc[mi][ni], 0, 0, 0);
            acc[mi][ni] = __builtin_amdgcn_mfma_f32_16x16x32_bf16(af[mi][1], bfr[ni][1], acc[mi][ni], 0, 0, 0);
        }
    // C/D layout (m89-verified): col = lane&15, row = (lane>>4)*4 + reg
#pragma unroll
    for (int mi = 0; mi < 4; mi++)
#pragma unroll
        for (int ni = 0; ni < 4; ni++) {
            int col = c0 + ni * 16 + lr;
            int rowb = r0 + mi * 16 + kg * 4;
#pragma unroll
            for (int r = 0; r < 4; r++) {
                float v = acc[mi][ni][r];
                out[(size_t)(rowb + r) * NNODES + col] = 1.f / (1.f + __expf(-v));
            }
        }
}

extern "C" void kernel_launch(void* const* d_in, const int* in_sizes, int n_in,
                              void* d_out, int out_size, void* d_ws, size_t ws_size,
                              hipStream_t stream) {
    (void)in_sizes; (void)n_in; (void)out_size; (void)ws_size;
    const float* x  = (const float*)d_in[0];
    const int* erow = (const int*)d_in[1];
    const int* ecol = (const int*)d_in[2];
    const float* ew = (const float*)d_in[3];
    const float* W1 = (const float*)d_in[4];
    const float* W2 = (const float*)d_in[5];
    const float* W3 = (const float*)d_in[6];
    float* z_igae = (float*)d_out;
    float* adj = (float*)d_out + (size_t)NNODES * 64;

    char* ws = (char*)d_ws;
    size_t off = 0;
    auto alloc = [&](size_t bytes) {
        void* p = ws + off;
        off += (bytes + 255) & ~(size_t)255;
        return p;
    };
    float* h1 = (float*)alloc((size_t)NNODES * 256 * 4);
    float* z1 = (float*)alloc((size_t)NNODES * 256 * 4);
    float* h2 = (float*)alloc((size_t)NNODES * 128 * 4);
    float* z2 = (float*)alloc((size_t)NNODES * 128 * 4);
    float* h3 = (float*)alloc((size_t)NNODES * 64 * 4);
    __hip_bfloat16* Zb = (__hip_bfloat16*)alloc((size_t)NNODES * 64 * 2);
    int* cnt = (int*)alloc(NNODES * 4);
    int* row_ptr = (int*)alloc((NNODES + 1) * 4);
    int* fill = (int*)alloc(NNODES * 4);
    int* col_s = (int*)alloc((size_t)NEDGES * 4);
    float* w_s = (float*)alloc((size_t)NEDGES * 4);

    // CSR build (per call; deterministic up to fp-summation order)
    hipMemsetAsync(cnt, 0, NNODES * 4, stream);
    hist_kernel<<<NEDGES / 256, 256, 0, stream>>>(erow, cnt);
    scan_kernel<<<1, 1024, 0, stream>>>(cnt, row_ptr, fill);
    scatter_kernel<<<NEDGES / 256, 256, 0, stream>>>(erow, ecol, ew, fill, col_s, w_s);

    // layer 1: h1 = tanh(x @ W1); z1 = spmm(h1)
    gemm_act<true><<<dim3(256 / 64, NNODES / 64), 256, 0, stream>>>(x, W1, h1, NNODES, 512, 256);
    spmm_kernel<256, false><<<NNODES, 256, 0, stream>>>(row_ptr, col_s, w_s, h1, z1, nullptr);
    // layer 2
    gemm_act<true><<<dim3(128 / 64, NNODES / 64), 256, 0, stream>>>(z1, W2, h2, NNODES, 256, 128);
    spmm_kernel<128, false><<<NNODES / 2, 256, 0, stream>>>(row_ptr, col_s, w_s, h2, z2, nullptr);
    // layer 3 (no tanh)
    gemm_act<false><<<dim3(64 / 64, NNODES / 64), 256, 0, stream>>>(z2, W3, h3, NNODES, 128, 64);
    spmm_kernel<64, true><<<NNODES / 4, 256, 0, stream>>>(row_ptr, col_s, w_s, h3, z_igae, Zb);
    // adjacency reconstruction
    zzt_sigmoid<<<dim3(NNODES / 256, NNODES / 64), 256, 0, stream>>>((const __bf16*)Zb, adj);
}

// Round 2
// 343.672 us; speedup vs baseline: 1.4502x; 1.4502x over previous
//
#include <hip/hip_runtime.h>
#include <hip/hip_bf16.h>

#define NNODES 12288
#define NEDGES (NNODES * 32)

typedef __attribute__((ext_vector_type(4))) float f32x4;
typedef __attribute__((ext_vector_type(8))) __bf16 bf16x8;

// ---------------- tiny utility kernels ----------------
__global__ void zero_kernel(int* __restrict__ p, int n) {
    int i = blockIdx.x * 256 + threadIdx.x;
    if (i < n) p[i] = 0;
}

// cast f32 -> bf16, 8 elems/thread
__global__ void cast_bf16_kernel(const float* __restrict__ in, __bf16* __restrict__ out, int n8) {
    int i = blockIdx.x * 256 + threadIdx.x;
    if (i >= n8) return;
    f32x4 a = ((const f32x4*)in)[i * 2];
    f32x4 b = ((const f32x4*)in)[i * 2 + 1];
    bf16x8 o;
#pragma unroll
    for (int j = 0; j < 4; j++) { o[j] = (__bf16)a[j]; o[4 + j] = (__bf16)b[j]; }
    ((bf16x8*)out)[i] = o;
}

// W[K,N] f32 -> Wt[N,K] bf16 (coalesced read, scattered 2B write; tiny matrices)
__global__ void wcast_kernel(const float* __restrict__ W, __bf16* __restrict__ Wt, int K, int N) {
    int idx = blockIdx.x * 256 + threadIdx.x;
    if (idx >= K * N) return;
    int k = idx / N, n = idx % N;
    Wt[(size_t)n * K + k] = (__bf16)W[idx];
}

// ---------------- CSR build ----------------
__global__ void hist_kernel(const int* __restrict__ row, int* __restrict__ cnt) {
    int e = blockIdx.x * 256 + threadIdx.x;
    atomicAdd(&cnt[row[e]], 1);
}

__global__ void scan_kernel(const int* __restrict__ cnt, int* __restrict__ row_ptr,
                            int* __restrict__ fill) {
    __shared__ int lds[1024];
    int t = threadIdx.x;
    int local[12];
    int s = 0;
#pragma unroll
    for (int i = 0; i < 12; i++) { local[i] = cnt[t * 12 + i]; s += local[i]; }
    lds[t] = s;
    __syncthreads();
    for (int off = 1; off < 1024; off <<= 1) {
        int v = lds[t];
        int add = (t >= off) ? lds[t - off] : 0;
        __syncthreads();
        lds[t] = v + add;
        __syncthreads();
    }
    int ex = (t == 0) ? 0 : lds[t - 1];
#pragma unroll
    for (int i = 0; i < 12; i++) {
        row_ptr[t * 12 + i] = ex;
        fill[t * 12 + i] = ex;
        ex += local[i];
    }
    if (t == 1023) row_ptr[NNODES] = ex;
}

__global__ void scatter_kernel(const int* __restrict__ row, const int* __restrict__ col,
                               const float* __restrict__ w, int* __restrict__ fill,
                               int* __restrict__ col_s, float* __restrict__ w_s) {
    int e = blockIdx.x * 256 + threadIdx.x;
    int r = row[e];
    int p = atomicAdd(&fill[r], 1);
    col_s[p] = col[e];
    w_s[p] = w[e];
}

// ---------------- dense layer GEMM: bf16 MFMA 16x16x32 ----------------
// C[M,Nc] = act(A[M,K] @ W[K,Nc]) with Wt = W^T stored [Nc,K] bf16.
// Block: 4 waves, each wave a 32x64 tile; block tile 128x64. No LDS.
template <bool TANH>
__global__ __launch_bounds__(256) void gemm_mfma(const __bf16* __restrict__ A,
                                                 const __bf16* __restrict__ Wt,
                                                 __bf16* __restrict__ C,
                                                 int M, int K, int Nc) {
    int wave = threadIdx.x >> 6, lane = threadIdx.x & 63;
    int lr = lane & 15;   // fragment row index (A: m, B: n)
    int kg = lane >> 4;   // k-group
    int m0 = blockIdx.y * 128 + wave * 32;
    int n0 = blockIdx.x * 64;
    f32x4 acc[2][4];
#pragma unroll
    for (int mi = 0; mi < 2; mi++)
#pragma unroll
        for (int ni = 0; ni < 4; ni++) acc[mi][ni] = (f32x4){0.f, 0.f, 0.f, 0.f};
    for (int k0 = 0; k0 < K; k0 += 32) {
        bf16x8 af[2], bf[4];
#pragma unroll
        for (int mi = 0; mi < 2; mi++)
            af[mi] = *(const bf16x8*)(A + (size_t)(m0 + mi * 16 + lr) * K + k0 + kg * 8);
#pragma unroll
        for (int ni = 0; ni < 4; ni++)
            bf[ni] = *(const bf16x8*)(Wt + (size_t)(n0 + ni * 16 + lr) * K + k0 + kg * 8);
#pragma unroll
        for (int mi = 0; mi < 2; mi++)
#pragma unroll
            for (int ni = 0; ni < 4; ni++)
                acc[mi][ni] = __builtin_amdgcn_mfma_f32_16x16x32_bf16(af[mi], bf[ni], acc[mi][ni], 0, 0, 0);
    }
    // C/D layout (m89-verified): col = lane&15, row = (lane>>4)*4 + reg
#pragma unroll
    for (int mi = 0; mi < 2; mi++)
#pragma unroll
        for (int ni = 0; ni < 4; ni++) {
            int col = n0 + ni * 16 + lr;
            int rowb = m0 + mi * 16 + kg * 4;
#pragma unroll
            for (int r = 0; r < 4; r++) {
                float v = acc[mi][ni][r];
                if (TANH) v = tanhf(v);
                C[(size_t)(rowb + r) * Nc + col] = (__bf16)v;
            }
        }
}

// ---------------- SpMM from CSR, bf16 gather, f32 accumulate ----------------
// out[r,f] = sum_e w_s[e] * h[col_s[e], f]; F/8 lanes per row, 8 feats/lane.
template <int F, bool FINAL>
__global__ __launch_bounds__(256) void spmm_bf16(const int* __restrict__ row_ptr,
                                                 const int* __restrict__ col_s,
                                                 const float* __restrict__ w_s,
                                                 const __bf16* __restrict__ h,
                                                 __bf16* __restrict__ z,
                                                 float* __restrict__ zf) {
    constexpr int L = F / 8;  // lanes per row
    int r = blockIdx.x * (256 / L) + threadIdx.x / L;
    int f8 = (threadIdx.x % L) * 8;
    int e0 = row_ptr[r], e1 = row_ptr[r + 1];
    float acc[8] = {};
    for (int e = e0; e < e1; e++) {
        float w = w_s[e];
        bf16x8 hv = *(const bf16x8*)(h + (size_t)col_s[e] * F + f8);
#pragma unroll
        for (int j = 0; j < 8; j++) acc[j] = fmaf(w, (float)hv[j], acc[j]);
    }
    bf16x8 o;
#pragma unroll
    for (int j = 0; j < 8; j++) o[j] = (__bf16)acc[j];
    *(bf16x8*)(z + (size_t)r * F + f8) = o;
    if (FINAL) {
        f32x4 o0, o1;
#pragma unroll
        for (int j = 0; j < 4; j++) { o0[j] = acc[j]; o1[j] = acc[4 + j]; }
        *(f32x4*)(zf + (size_t)r * F + f8) = o0;
        *(f32x4*)(zf + (size_t)r * F + f8 + 4) = o1;
    }
}

// ---------------- adj = sigmoid(Z Z^T), Z bf16 [N,64], MFMA 16x16x32 ----------------
__global__ __launch_bounds__(256) void zzt_sigmoid(const __bf16* __restrict__ Z,
                                                   float* __restrict__ out) {
    int wave = threadIdx.x >> 6;
    int lane = threadIdx.x & 63;
    int lr = lane & 15;
    int kg = lane >> 4;
    int r0 = blockIdx.y * 64;
    int c0 = blockIdx.x * 256 + wave * 64;
    bf16x8 af[4][2], bfr[4][2];
#pragma unroll
    for (int i = 0; i < 4; i++)
#pragma unroll
        for (int ks = 0; ks < 2; ks++) {
            af[i][ks]  = *(const bf16x8*)(Z + (size_t)(r0 + i * 16 + lr) * 64 + ks * 32 + kg * 8);
            bfr[i][ks] = *(const bf16x8*)(Z + (size_t)(c0 + i * 16 + lr) * 64 + ks * 32 + kg * 8);
        }
    f32x4 acc[4][4];
#pragma unroll
    for (int mi = 0; mi < 4; mi++)
#pragma unroll
        for (int ni = 0; ni < 4; ni++) acc[mi][ni] = (f32x4){0.f, 0.f, 0.f, 0.f};
#pragma unroll
    for (int mi = 0; mi < 4; mi++)
#pragma unroll
        for (int ni = 0; ni < 4; ni++) {
            acc[mi][ni] = __builtin_amdgcn_mfma_f32_16x16x32_bf16(af[mi][0], bfr[ni][0], acc[mi][ni], 0, 0, 0);
            acc[mi][ni] = __builtin_amdgcn_mfma_f32_16x16x32_bf16(af[mi][1], bfr[ni][1], acc[mi][ni], 0, 0, 0);
        }
#pragma unroll
    for (int mi = 0; mi < 4; mi++)
#pragma unroll
        for (int ni = 0; ni < 4; ni++) {
            int col = c0 + ni * 16 + lr;
            int rowb = r0 + mi * 16 + kg * 4;
#pragma unroll
            for (int r = 0; r < 4; r++) {
                float v = acc[mi][ni][r];
                out[(size_t)(rowb + r) * NNODES + col] = 1.f / (1.f + __expf(-v));
            }
        }
}

extern "C" void kernel_launch(void* const* d_in, const int* in_sizes, int n_in,
                              void* d_out, int out_size, void* d_ws, size_t ws_size,
                              hipStream_t stream) {
    (void)in_sizes; (void)n_in; (void)out_size; (void)ws_size;
    const float* x  = (const float*)d_in[0];
    const int* erow = (const int*)d_in[1];
    const int* ecol = (const int*)d_in[2];
    const float* ew = (const float*)d_in[3];
    const float* W1 = (const float*)d_in[4];
    const float* W2 = (const float*)d_in[5];
    const float* W3 = (const float*)d_in[6];
    float* z_igae = (float*)d_out;
    float* adj = (float*)d_out + (size_t)NNODES * 64;

    char* ws = (char*)d_ws;
    size_t off = 0;
    auto alloc = [&](size_t bytes) {
        void* p = ws + off;
        off += (bytes + 255) & ~(size_t)255;
        return p;
    };
    __bf16* xb  = (__bf16*)alloc((size_t)NNODES * 512 * 2);
    __bf16* W1t = (__bf16*)alloc((size_t)512 * 256 * 2);
    __bf16* W2t = (__bf16*)alloc((size_t)256 * 128 * 2);
    __bf16* W3t = (__bf16*)alloc((size_t)128 * 64 * 2);
    __bf16* h1  = (__bf16*)alloc((size_t)NNODES * 256 * 2);
    __bf16* z1  = (__bf16*)alloc((size_t)NNODES * 256 * 2);
    __bf16* h2  = (__bf16*)alloc((size_t)NNODES * 128 * 2);
    __bf16* z2  = (__bf16*)alloc((size_t)NNODES * 128 * 2);
    __bf16* h3  = (__bf16*)alloc((size_t)NNODES * 64 * 2);
    __bf16* Zb  = (__bf16*)alloc((size_t)NNODES * 64 * 2);
    int* cnt     = (int*)alloc(NNODES * 4);
    int* row_ptr = (int*)alloc((NNODES + 1) * 4);
    int* fill    = (int*)alloc(NNODES * 4);
    int* col_s   = (int*)alloc((size_t)NEDGES * 4);
    float* w_s   = (float*)alloc((size_t)NEDGES * 4);

    // CSR build
    zero_kernel<<<(NNODES + 255) / 256, 256, 0, stream>>>(cnt, NNODES);
    hist_kernel<<<NEDGES / 256, 256, 0, stream>>>(erow, cnt);
    scan_kernel<<<1, 1024, 0, stream>>>(cnt, row_ptr, fill);
    scatter_kernel<<<NEDGES / 256, 256, 0, stream>>>(erow, ecol, ew, fill, col_s, w_s);

    // precision casts
    cast_bf16_kernel<<<(NNODES * 512 / 8 + 255) / 256, 256, 0, stream>>>(x, xb, NNODES * 512 / 8);
    wcast_kernel<<<(512 * 256 + 255) / 256, 256, 0, stream>>>(W1, W1t, 512, 256);
    wcast_kernel<<<(256 * 128 + 255) / 256, 256, 0, stream>>>(W2, W2t, 256, 128);
    wcast_kernel<<<(128 * 64 + 255) / 256, 256, 0, stream>>>(W3, W3t, 128, 64);

    // layer 1: h1 = tanh(xb @ W1); z1 = spmm(h1)
    gemm_mfma<true><<<dim3(256 / 64, NNODES / 128), 256, 0, stream>>>(xb, W1t, h1, NNODES, 512, 256);
    spmm_bf16<256, false><<<NNODES / 8, 256, 0, stream>>>(row_ptr, col_s, w_s, h1, z1, nullptr);
    // layer 2
    gemm_mfma<true><<<dim3(128 / 64, NNODES / 128), 256, 0, stream>>>(z1, W2t, h2, NNODES, 256, 128);
    spmm_bf16<128, false><<<NNODES / 16, 256, 0, stream>>>(row_ptr, col_s, w_s, h2, z2, nullptr);
    // layer 3 (no tanh)
    gemm_mfma<false><<<dim3(64 / 64, NNODES / 128), 256, 0, stream>>>(z2, W3t, h3, NNODES, 128, 64);
    spmm_bf16<64, true><<<NNODES / 32, 256, 0, stream>>>(row_ptr, col_s, w_s, h3, Zb, z_igae);
    // adjacency reconstruction
    zzt_sigmoid<<<dim3(NNODES / 256, NNODES / 64), 256, 0, stream>>>((const __bf16*)Zb, adj);
}

// Round 3
// 245.657 us; speedup vs baseline: 2.0288x; 1.3990x over previous
//
#include <hip/hip_runtime.h>
#include <hip/hip_bf16.h>

#define NNODES 12288
#define NEDGES (NNODES * 32)
#define ELLCAP 128  // max degree ~60 (Binomial(E,1/N)); 128 is unreachable

typedef __attribute__((ext_vector_type(4))) float f32x4;
typedef __attribute__((ext_vector_type(8))) __bf16 bf16x8;

// ---------------- fused prep: zero deg + 3 weight transpose-casts ----------------
// thread space: [0,NNODES) zero deg; then W1 (512x256), W2 (256x128), W3 (128x64)
__global__ __launch_bounds__(256) void prep_kernel(const float* __restrict__ W1,
                                                   const float* __restrict__ W2,
                                                   const float* __restrict__ W3,
                                                   __bf16* __restrict__ W1t,
                                                   __bf16* __restrict__ W2t,
                                                   __bf16* __restrict__ W3t,
                                                   int* __restrict__ deg) {
    int i = blockIdx.x * 256 + threadIdx.x;
    if (i < NNODES) { deg[i] = 0; return; }
    int j = i - NNODES;
    if (j < 512 * 256) { W1t[(size_t)(j % 256) * 512 + j / 256] = (__bf16)W1[j]; return; }
    j -= 512 * 256;
    if (j < 256 * 128) { W2t[(size_t)(j % 128) * 256 + j / 128] = (__bf16)W2[j]; return; }
    j -= 256 * 128;
    if (j < 128 * 64) { W3t[(size_t)(j % 64) * 128 + j / 64] = (__bf16)W3[j]; return; }
}

// ---------------- ELL build: one pass, no scan ----------------
__global__ __launch_bounds__(256) void scatter_ell(const int* __restrict__ row,
                                                   const int* __restrict__ col,
                                                   const float* __restrict__ w,
                                                   int* __restrict__ deg,
                                                   int2* __restrict__ ell) {
    int e = blockIdx.x * 256 + threadIdx.x;
    int r = row[e];
    int p = atomicAdd(&deg[r], 1);
    int2 cw; cw.x = col[e]; cw.y = __float_as_int(w[e]);
    ell[(size_t)r * ELLCAP + p] = cw;
}

// ---------------- dense layer GEMM: bf16 MFMA 16x16x32, f32 A input ----------------
// C[M,Nc] = act(A[M,K] @ W[K,Nc]); Wt = W^T [Nc,K] bf16; A is f32, cast in-register.
// 4 waves, wave tile 32x64, block tile 128x64. K compile-time -> full unroll.
template <bool TANH, int K, bool A_F32>
__global__ __launch_bounds__(256) void gemm_mfma(const void* __restrict__ Av,
                                                 const __bf16* __restrict__ Wt,
                                                 __bf16* __restrict__ C, int Nc) {
    int wave = threadIdx.x >> 6, lane = threadIdx.x & 63;
    int lr = lane & 15;
    int kg = lane >> 4;
    int m0 = blockIdx.y * 128 + wave * 32;
    int n0 = blockIdx.x * 64;
    f32x4 acc[2][4];
#pragma unroll
    for (int mi = 0; mi < 2; mi++)
#pragma unroll
        for (int ni = 0; ni < 4; ni++) acc[mi][ni] = (f32x4){0.f, 0.f, 0.f, 0.f};
#pragma unroll
    for (int k0 = 0; k0 < K; k0 += 32) {
        bf16x8 af[2], bf[4];
#pragma unroll
        for (int mi = 0; mi < 2; mi++) {
            if (A_F32) {
                const float* ap = (const float*)Av + (size_t)(m0 + mi * 16 + lr) * K + k0 + kg * 8;
                f32x4 a0 = *(const f32x4*)ap;
                f32x4 a1 = *(const f32x4*)(ap + 4);
#pragma unroll
                for (int j = 0; j < 4; j++) { af[mi][j] = (__bf16)a0[j]; af[mi][4 + j] = (__bf16)a1[j]; }
            } else {
                af[mi] = *(const bf16x8*)((const __bf16*)Av + (size_t)(m0 + mi * 16 + lr) * K + k0 + kg * 8);
            }
        }
#pragma unroll
        for (int ni = 0; ni < 4; ni++)
            bf[ni] = *(const bf16x8*)(Wt + (size_t)(n0 + ni * 16 + lr) * K + k0 + kg * 8);
#pragma unroll
        for (int mi = 0; mi < 2; mi++)
#pragma unroll
            for (int ni = 0; ni < 4; ni++)
                acc[mi][ni] = __builtin_amdgcn_mfma_f32_16x16x32_bf16(af[mi], bf[ni], acc[mi][ni], 0, 0, 0);
    }
    // C/D layout (m89-verified): col = lane&15, row = (lane>>4)*4 + reg
#pragma unroll
    for (int mi = 0; mi < 2; mi++)
#pragma unroll
        for (int ni = 0; ni < 4; ni++) {
            int col = n0 + ni * 16 + lr;
            int rowb = m0 + mi * 16 + kg * 4;
#pragma unroll
            for (int r = 0; r < 4; r++) {
                float v = acc[mi][ni][r];
                if (TANH) v = tanhf(v);
                C[(size_t)(rowb + r) * Nc + col] = (__bf16)v;
            }
        }
}

// ---------------- SpMM from ELL, bf16 gather, f32 accumulate ----------------
template <int F, bool FINAL>
__global__ __launch_bounds__(256) void spmm_ell(const int* __restrict__ deg,
                                                const int2* __restrict__ ell,
                                                const __bf16* __restrict__ h,
                                                __bf16* __restrict__ z,
                                                float* __restrict__ zf) {
    constexpr int L = F / 8;  // lanes per row
    int r = blockIdx.x * (256 / L) + threadIdx.x / L;
    int f8 = (threadIdx.x % L) * 8;
    int d = deg[r];
    const int2* er = ell + (size_t)r * ELLCAP;
    float acc[8] = {};
#pragma unroll 4
    for (int e = 0; e < d; e++) {
        int2 cw = er[e];
        float w = __int_as_float(cw.y);
        bf16x8 hv = *(const bf16x8*)(h + (size_t)cw.x * F + f8);
#pragma unroll
        for (int j = 0; j < 8; j++) acc[j] = fmaf(w, (float)hv[j], acc[j]);
    }
    bf16x8 o;
#pragma unroll
    for (int j = 0; j < 8; j++) o[j] = (__bf16)acc[j];
    *(bf16x8*)(z + (size_t)r * F + f8) = o;
    if (FINAL) {
        f32x4 o0, o1;
#pragma unroll
        for (int j = 0; j < 4; j++) { o0[j] = acc[j]; o1[j] = acc[4 + j]; }
        *(f32x4*)(zf + (size_t)r * F + f8) = o0;
        *(f32x4*)(zf + (size_t)r * F + f8 + 4) = o1;
    }
}

// ---------------- adj = sigmoid(Z Z^T), Z bf16 [N,64], MFMA 16x16x32 ----------------
__global__ __launch_bounds__(256) void zzt_sigmoid(const __bf16* __restrict__ Z,
                                                   float* __restrict__ out) {
    int wave = threadIdx.x >> 6;
    int lane = threadIdx.x & 63;
    int lr = lane & 15;
    int kg = lane >> 4;
    int r0 = blockIdx.y * 64;
    int c0 = blockIdx.x * 256 + wave * 64;
    bf16x8 af[4][2], bfr[4][2];
#pragma unroll
    for (int i = 0; i < 4; i++)
#pragma unroll
        for (int ks = 0; ks < 2; ks++) {
            af[i][ks]  = *(const bf16x8*)(Z + (size_t)(r0 + i * 16 + lr) * 64 + ks * 32 + kg * 8);
            bfr[i][ks] = *(const bf16x8*)(Z + (size_t)(c0 + i * 16 + lr) * 64 + ks * 32 + kg * 8);
        }
    f32x4 acc[4][4];
#pragma unroll
    for (int mi = 0; mi < 4; mi++)
#pragma unroll
        for (int ni = 0; ni < 4; ni++) acc[mi][ni] = (f32x4){0.f, 0.f, 0.f, 0.f};
#pragma unroll
    for (int mi = 0; mi < 4; mi++)
#pragma unroll
        for (int ni = 0; ni < 4; ni++) {
            acc[mi][ni] = __builtin_amdgcn_mfma_f32_16x16x32_bf16(af[mi][0], bfr[ni][0], acc[mi][ni], 0, 0, 0);
            acc[mi][ni] = __builtin_amdgcn_mfma_f32_16x16x32_bf16(af[mi][1], bfr[ni][1], acc[mi][ni], 0, 0, 0);
        }
#pragma unroll
    for (int mi = 0; mi < 4; mi++)
#pragma unroll
        for (int ni = 0; ni < 4; ni++) {
            int col = c0 + ni * 16 + lr;
            int rowb = r0 + mi * 16 + kg * 4;
#pragma unroll
            for (int r = 0; r < 4; r++) {
                float e = __expf(-acc[mi][ni][r]);
                out[(size_t)(rowb + r) * NNODES + col] = __builtin_amdgcn_rcpf(1.f + e);
            }
        }
}

extern "C" void kernel_launch(void* const* d_in, const int* in_sizes, int n_in,
                              void* d_out, int out_size, void* d_ws, size_t ws_size,
                              hipStream_t stream) {
    (void)in_sizes; (void)n_in; (void)out_size; (void)ws_size;
    const float* x  = (const float*)d_in[0];
    const int* erow = (const int*)d_in[1];
    const int* ecol = (const int*)d_in[2];
    const float* ew = (const float*)d_in[3];
    const float* W1 = (const float*)d_in[4];
    const float* W2 = (const float*)d_in[5];
    const float* W3 = (const float*)d_in[6];
    float* z_igae = (float*)d_out;
    float* adj = (float*)d_out + (size_t)NNODES * 64;

    char* ws = (char*)d_ws;
    size_t off = 0;
    auto alloc = [&](size_t bytes) {
        void* p = ws + off;
        off += (bytes + 255) & ~(size_t)255;
        return p;
    };
    __bf16* W1t = (__bf16*)alloc((size_t)512 * 256 * 2);
    __bf16* W2t = (__bf16*)alloc((size_t)256 * 128 * 2);
    __bf16* W3t = (__bf16*)alloc((size_t)128 * 64 * 2);
    __bf16* h1  = (__bf16*)alloc((size_t)NNODES * 256 * 2);
    __bf16* z1  = (__bf16*)alloc((size_t)NNODES * 256 * 2);
    __bf16* h2  = (__bf16*)alloc((size_t)NNODES * 128 * 2);
    __bf16* z2  = (__bf16*)alloc((size_t)NNODES * 128 * 2);
    __bf16* h3  = (__bf16*)alloc((size_t)NNODES * 64 * 2);
    __bf16* Zb  = (__bf16*)alloc((size_t)NNODES * 64 * 2);
    int* deg    = (int*)alloc(NNODES * 4);
    int2* ell   = (int2*)alloc((size_t)NNODES * ELLCAP * 8);

    // prep (zero deg + weight casts), then ELL build
    prep_kernel<<<(NNODES + 512 * 256 + 256 * 128 + 128 * 64 + 255) / 256, 256, 0, stream>>>(
        W1, W2, W3, W1t, W2t, W3t, deg);
    scatter_ell<<<NEDGES / 256, 256, 0, stream>>>(erow, ecol, ew, deg, ell);

    // layer 1: h1 = tanh(x @ W1) (f32 A cast in-register); z1 = spmm(h1)
    gemm_mfma<true, 512, true><<<dim3(256 / 64, NNODES / 128), 256, 0, stream>>>(x, W1t, h1, 256);
    spmm_ell<256, false><<<NNODES / 8, 256, 0, stream>>>(deg, ell, h1, z1, nullptr);
    // layer 2
    gemm_mfma<true, 256, false><<<dim3(128 / 64, NNODES / 128), 256, 0, stream>>>(z1, W2t, h2, 128);
    spmm_ell<128, false><<<NNODES / 16, 256, 0, stream>>>(deg, ell, h2, z2, nullptr);
    // layer 3 (no tanh)
    gemm_mfma<false, 128, false><<<dim3(64 / 64, NNODES / 128), 256, 0, stream>>>(z2, W3t, h3, 64);
    spmm_ell<64, true><<<NNODES / 32, 256, 0, stream>>>(deg, ell, h3, Zb, z_igae);
    // adjacency reconstruction
    zzt_sigmoid<<<dim3(NNODES / 256, NNODES / 64), 256, 0, stream>>>((const __bf16*)Zb, adj);
}